// Round 7
// baseline (324.762 us; speedup 1.0000x reference)
//
#include <hip/hip_runtime.h>

#define B_   2
#define N_   32768
#define M_   4096
#define C_   128
#define OUT_ 128
#define IN_  131

#define NSPLIT 16
#define MCHUNK (M_ / NSPLIT)     // 256 points per split
#define QPT    4                 // queries per thread in nn kernel
#define NQ     (B_ * N_)         // 65536 total queries

// ---------------------------------------------------------------------------
// K0: pack sampled points as (s0,s1,s2,|s|^2) float4, |s|^2 in the reference's
// exact rounding order.
// ---------------------------------------------------------------------------
__global__ __launch_bounds__(256) void pack_kernel(const float* __restrict__ sx,
                                                   float4* __restrict__ packed) {
    const int t = blockIdx.x * 256 + threadIdx.x;   // [0, B_*M_)
    if (t >= B_ * M_) return;
    float s0 = sx[3*t+0], s1 = sx[3*t+1], s2 = sx[3*t+2];
    float ss = __fadd_rn(__fadd_rn(__fmul_rn(s0,s0), __fmul_rn(s1,s1)),
                         __fmul_rn(s2,s2));
    packed[t] = make_float4(s0, s1, s2, ss);
}

// ---------------------------------------------------------------------------
// K1: split brute-force 3-NN, BRANCHLESS top-3 update. (byte-identical to R6)
// ---------------------------------------------------------------------------
__global__ __launch_bounds__(256) void nn_split_kernel(const float* __restrict__ x,
                                                       const float4* __restrict__ packed,
                                                       float4* __restrict__ part_d,
                                                       int4* __restrict__ part_i) {
    __shared__ float4 spts[MCHUNK];   // 4 KB
    const int split = blockIdx.x & (NSPLIT - 1);
    const int qb    = blockIdx.x >> 4;
    const int q0    = qb * 1024;
    const int b     = q0 >> 15;                     // N_=32768
    const int t     = threadIdx.x;

    spts[t] = packed[(size_t)b * M_ + split * MCHUNK + t];
    __syncthreads();

    float x0[QPT], x1[QPT], x2[QPT], xx[QPT];
    float bd0[QPT], bd1[QPT], bd2[QPT];
    int   bi0[QPT], bi1[QPT], bi2[QPT];
    #pragma unroll
    for (int qq = 0; qq < QPT; ++qq) {
        const int qi = q0 + qq * 256 + t;
        x0[qq] = x[(size_t)qi*3+0];
        x1[qq] = x[(size_t)qi*3+1];
        x2[qq] = x[(size_t)qi*3+2];
        xx[qq] = __fadd_rn(__fadd_rn(__fmul_rn(x0[qq],x0[qq]),
                                     __fmul_rn(x1[qq],x1[qq])),
                           __fmul_rn(x2[qq],x2[qq]));
        bd0[qq] = 1e30f; bd1[qq] = 1e30f; bd2[qq] = 1e30f;
        bi0[qq] = 0;     bi1[qq] = 0;     bi2[qq] = 0;
    }

    const int m_base = split * MCHUNK;
    #pragma unroll 4
    for (int j = 0; j < MCHUNK; ++j) {
        float4 s = spts[j];
        const int m = m_base + j;
        #pragma unroll
        for (int qq = 0; qq < QPT; ++qq) {
            float dot = __fadd_rn(__fadd_rn(__fmul_rn(x0[qq],s.x),
                                            __fmul_rn(x1[qq],s.y)),
                                  __fmul_rn(x2[qq],s.z));
            float d2 = __fadd_rn(__fmaf_rn(-2.0f, dot, xx[qq]), s.w);
            const float k0 = bd0[qq], k1 = bd1[qq], k2 = bd2[qq];
            const bool c0 = d2 < k0, c1 = d2 < k1, c2 = d2 < k2;
            bi2[qq] = c1 ? bi1[qq] : (c2 ? m : bi2[qq]);
            bi1[qq] = c0 ? bi0[qq] : (c1 ? m : bi1[qq]);
            bi0[qq] = c0 ? m : bi0[qq];
            bd0[qq] = fminf(k0, d2);
            bd1[qq] = __builtin_amdgcn_fmed3f(d2, k0, k1);
            bd2[qq] = __builtin_amdgcn_fmed3f(d2, k1, k2);
        }
    }

    #pragma unroll
    for (int qq = 0; qq < QPT; ++qq) {
        const int qi = q0 + qq * 256 + t;
        part_d[(size_t)split * NQ + qi] = make_float4(bd0[qq], bd1[qq], bd2[qq], 0.f);
        part_i[(size_t)split * NQ + qi] = make_int4 (bi0[qq], bi1[qq], bi2[qq], 0);
    }
}

// ---------------------------------------------------------------------------
// K1b: merge 16 partial top-3s per query. Ascending-m order + strict '<' ->
// first-wins tie handling, identical to a single pass over all 4096 points.
// ---------------------------------------------------------------------------
__device__ __forceinline__ void ins3(float d, int m, float& b0, float& b1, float& b2,
                                     int& i0, int& i1, int& i2) {
    if (d < b2) {
        if (d < b1) {
            b2 = b1; i2 = i1;
            if (d < b0) { b1 = b0; i1 = i0; b0 = d; i0 = m; }
            else        { b1 = d;  i1 = m; }
        } else { b2 = d; i2 = m; }
    }
}

__global__ __launch_bounds__(256) void merge_kernel(const float4* __restrict__ part_d,
                                                    const int4* __restrict__ part_i,
                                                    int4* __restrict__ idx_out) {
    const int q = blockIdx.x * 256 + threadIdx.x;
    float b0 = 1e30f, b1 = 1e30f, b2 = 1e30f;
    int   i0 = 0,     i1 = 0,     i2 = 0;
    #pragma unroll
    for (int s = 0; s < NSPLIT; ++s) {
        float4 d = part_d[(size_t)s * NQ + q];
        int4   i = part_i[(size_t)s * NQ + q];
        ins3(d.x, i.x, b0, b1, b2, i0, i1, i2);
        ins3(d.y, i.y, b0, b1, b2, i0, i1, i2);
        ins3(d.z, i.z, b0, b1, b2, i0, i1, i2);
    }
    idx_out[q] = make_int4(i0, i1, i2, 0);
}

// ---------------------------------------------------------------------------
// K2 (fused): interp-gather + gemm1(relu, xyz-fold) + gemm2 + transposed store.
// Per block: 128 queries. Persistent LDS tile sT[k][row] (67KB) holds I, then
// is overwritten with H for gemm2 -- no I/A HBM round-trips (saves 128 MB).
// All FP expressions are char-identical to the previously-passing kernels.
// ---------------------------------------------------------------------------
__global__ __launch_bounds__(256) void fused_mlp_kernel(const float* __restrict__ features,
                                                        const int4* __restrict__ idx,
                                                        const float* __restrict__ x,
                                                        const float* __restrict__ w1,
                                                        const float* __restrict__ b1,
                                                        const float* __restrict__ w2,
                                                        const float* __restrict__ b2,
                                                        float* __restrict__ out) {
    __shared__ float sT[128][132];   // [k][row], 67.6 KB: I-tile, then H-tile
    __shared__ float sW[16][132];    // weight chunk [k][out], 8.4 KB
    const int row0 = blockIdx.x * 128;
    const int tid  = threadIdx.x;
    const int tr   = tid & 15;
    const int tc   = tid >> 4;
    const int b    = row0 >> 15;

    // ---- Phase 0: gather 3 neighbor rows, average, write I into sT[k][q] ----
    {
        const int q    = tid >> 1;          // query within tile [0,128)
        const int half = tid & 1;           // which 16 float4-cols
        const int4 v   = idx[row0 + q];
        const float4* fb = (const float4*)features + (size_t)b * M_ * (C_/4);
        const float4* r0 = fb + (size_t)v.x * 32;
        const float4* r1 = fb + (size_t)v.y * 32;
        const float4* r2 = fb + (size_t)v.z * 32;
        #pragma unroll
        for (int u = 0; u < 16; ++u) {
            const int c4 = half * 16 + u;
            float4 f0 = r0[c4], f1 = r1[c4], f2 = r2[c4];
            sT[c4*4+0][q] = ((f0.x + f1.x) + f2.x) / 3.0f;
            sT[c4*4+1][q] = ((f0.y + f1.y) + f2.y) / 3.0f;
            sT[c4*4+2][q] = ((f0.z + f1.z) + f2.z) / 3.0f;
            sT[c4*4+3][q] = ((f0.w + f1.w) + f2.w) / 3.0f;
        }
    }
    __syncthreads();

    // ---- Phase 1: gemm1 from sT, w1 chunks staged per-kc ----
    float acc[8][8] = {};
    for (int kc = 0; kc < 8; ++kc) {
        {
            int o = tid >> 1, kk0 = (tid & 1) * 8;
            #pragma unroll
            for (int kk = 0; kk < 8; ++kk)
                sW[kk0+kk][o] = w1[(size_t)o * IN_ + 3 + kc*16 + kk0 + kk];
        }
        __syncthreads();
        #pragma unroll
        for (int kk = 0; kk < 16; ++kk) {
            float4 a0 = *(const float4*)&sT[kc*16+kk][tr*8];
            float4 a1 = *(const float4*)&sT[kc*16+kk][tr*8+4];
            float4 c0 = *(const float4*)&sW[kk][tc*8];
            float4 c1 = *(const float4*)&sW[kk][tc*8+4];
            float av[8] = {a0.x,a0.y,a0.z,a0.w,a1.x,a1.y,a1.z,a1.w};
            float bv[8] = {c0.x,c0.y,c0.z,c0.w,c1.x,c1.y,c1.z,c1.w};
            #pragma unroll
            for (int i = 0; i < 8; ++i)
                #pragma unroll
                for (int j = 0; j < 8; ++j)
                    acc[i][j] = fmaf(av[i], bv[j], acc[i][j]);
        }
        __syncthreads();
    }

    // ---- epilogue 1: xyz columns + bias + relu (registers) ----
    {
        float wx0[8], wx1[8], wx2[8], bb[8];
        #pragma unroll
        for (int j = 0; j < 8; ++j) {
            int o = tc*8 + j;
            wx0[j] = w1[(size_t)o*IN_+0];
            wx1[j] = w1[(size_t)o*IN_+1];
            wx2[j] = w1[(size_t)o*IN_+2];
            bb[j]  = b1[o];
        }
        #pragma unroll
        for (int i = 0; i < 8; ++i) {
            int r = row0 + tr*8 + i;
            float x0 = x[(size_t)r*3+0], x1 = x[(size_t)r*3+1], x2 = x[(size_t)r*3+2];
            #pragma unroll
            for (int j = 0; j < 8; ++j) {
                float v = acc[i][j] + wx0[j]*x0 + wx1[j]*x1 + wx2[j]*x2 + bb[j];
                acc[i][j] = v > 0.0f ? v : 0.0f;
            }
        }
    }

    // ---- Phase 2: write H into sT[o][row] ----
    #pragma unroll
    for (int i = 0; i < 8; ++i)
        #pragma unroll
        for (int j = 0; j < 8; ++j)
            sT[tc*8+j][tr*8+i] = acc[i][j];
    __syncthreads();

    // ---- Phase 3: gemm2 from sT, w2 chunks staged per-kc ----
    float acc2[8][8] = {};
    for (int kc = 0; kc < 8; ++kc) {
        {
            int o = tid >> 1, kq = tid & 1;
            float4 h0 = *(const float4*)&w2[(size_t)o * OUT_ + kc*16 + kq*8];
            float4 h1 = *(const float4*)&w2[(size_t)o * OUT_ + kc*16 + kq*8 + 4];
            sW[kq*8+0][o] = h0.x; sW[kq*8+1][o] = h0.y;
            sW[kq*8+2][o] = h0.z; sW[kq*8+3][o] = h0.w;
            sW[kq*8+4][o] = h1.x; sW[kq*8+5][o] = h1.y;
            sW[kq*8+6][o] = h1.z; sW[kq*8+7][o] = h1.w;
        }
        __syncthreads();
        #pragma unroll
        for (int kk = 0; kk < 16; ++kk) {
            float4 a0 = *(const float4*)&sT[kc*16+kk][tr*8];
            float4 a1 = *(const float4*)&sT[kc*16+kk][tr*8+4];
            float4 c0 = *(const float4*)&sW[kk][tc*8];
            float4 c1 = *(const float4*)&sW[kk][tc*8+4];
            float av[8] = {a0.x,a0.y,a0.z,a0.w,a1.x,a1.y,a1.z,a1.w};
            float bv[8] = {c0.x,c0.y,c0.z,c0.w,c1.x,c1.y,c1.z,c1.w};
            #pragma unroll
            for (int i = 0; i < 8; ++i)
                #pragma unroll
                for (int j = 0; j < 8; ++j)
                    acc2[i][j] = fmaf(av[i], bv[j], acc2[i][j]);
        }
        __syncthreads();
    }

    // ---- epilogue 2: bias + transposed store out[b][o][n] ----
    const int n0 = (row0 & (N_-1)) + tr*8;
    #pragma unroll
    for (int j = 0; j < 8; ++j) {
        int o = tc*8 + j;
        float bias = b2[o];
        float4 o0 = make_float4(acc2[0][j]+bias, acc2[1][j]+bias,
                                acc2[2][j]+bias, acc2[3][j]+bias);
        float4 o1 = make_float4(acc2[4][j]+bias, acc2[5][j]+bias,
                                acc2[6][j]+bias, acc2[7][j]+bias);
        float* dst = out + (((size_t)(b*OUT_ + o)) << 15) + n0;
        *(float4*)dst       = o0;
        *(float4*)(dst + 4) = o1;
    }
}

extern "C" void kernel_launch(void* const* d_in, const int* in_sizes, int n_in,
                              void* d_out, int out_size, void* d_ws, size_t ws_size,
                              hipStream_t stream) {
    const float* x        = (const float*)d_in[0];   // [B,N,3]
    const float* sx       = (const float*)d_in[1];   // [B,M,3]
    const float* features = (const float*)d_in[2];   // [B,M,C]
    const float* w1       = (const float*)d_in[3];   // [128,131]
    const float* b1       = (const float*)d_in[4];   // [128]
    const float* w2       = (const float*)d_in[5];   // [128,128]
    const float* b2       = (const float*)d_in[6];   // [128]
    float* out = (float*)d_out;                      // [B,128,N]

    char* ws = (char*)d_ws;
    // Layout:
    //   [0,1MB)     idx      (written by merge)
    //   [1,2MB)     packed   (dead after nn_split)
    //   [33,49MB)   part_d
    //   [49,65MB)   part_i
    int4*   idxb   = (int4*)ws;
    float4* packed = (float4*)(ws + (1u  << 20));
    float4* part_d = (float4*)(ws + (33u << 20));            // 16 MB
    int4*   part_i = (int4*) (ws + (33u << 20) + (16u<<20)); // 16 MB

    pack_kernel    <<<dim3((B_*M_ + 255)/256), dim3(256), 0, stream>>>(sx, packed);
    nn_split_kernel<<<dim3((NQ/1024) * NSPLIT), dim3(256), 0, stream>>>(x, packed, part_d, part_i);
    merge_kernel   <<<dim3(NQ/256), dim3(256), 0, stream>>>(part_d, part_i, idxb);
    fused_mlp_kernel<<<dim3(NQ/128), dim3(256), 0, stream>>>(features, idxb, x,
                                                             w1, b1, w2, b2, out);
}

// Round 8
// 298.197 us; speedup vs baseline: 1.0891x; 1.0891x over previous
//
#include <hip/hip_runtime.h>

#define B_   2
#define N_   32768
#define M_   4096
#define C_   128
#define OUT_ 128
#define IN_  131

#define NSPLIT 16
#define MCHUNK (M_ / NSPLIT)     // 256 points per split
#define NQ     (B_ * N_)         // 65536 total queries

// ---------------------------------------------------------------------------
// K0: pack sampled points as (s0,s1,s2,|s|^2) float4, |s|^2 in the reference's
// exact rounding order.
// ---------------------------------------------------------------------------
__global__ __launch_bounds__(256) void pack_kernel(const float* __restrict__ sx,
                                                   float4* __restrict__ packed) {
    const int t = blockIdx.x * 256 + threadIdx.x;   // [0, B_*M_)
    if (t >= B_ * M_) return;
    float s0 = sx[3*t+0], s1 = sx[3*t+1], s2 = sx[3*t+2];
    float ss = __fadd_rn(__fadd_rn(__fmul_rn(s0,s0), __fmul_rn(s1,s1)),
                         __fmul_rn(s2,s2));
    packed[t] = make_float4(s0, s1, s2, ss);
}

// ---------------------------------------------------------------------------
// K1: split brute-force 3-NN, branchless top-3, EXPLICIT SCALAR state.
// R7 evidence: VGPR_Count=36 < live state (40+) with [QPT] arrays -> compiler
// failed array->reg promotion and shuffled state (44.5 effective insts/pair
// vs 18 in source). Named scalars force promotion. FP expressions are
// char-identical to the R6/R7 passing kernel (same rounding, same tie order).
// ---------------------------------------------------------------------------
#define NN_DECL(X)                                                        \
    float x0##X, x1##X, x2##X, xx##X;                                     \
    float bd0##X = 1e30f, bd1##X = 1e30f, bd2##X = 1e30f;                 \
    int   bi0##X = 0,     bi1##X = 0,     bi2##X = 0;

#define NN_LOAD(X, QQ) {                                                  \
    const int qi = q0 + (QQ) * 256 + t;                                   \
    x0##X = x[(size_t)qi*3+0];                                            \
    x1##X = x[(size_t)qi*3+1];                                            \
    x2##X = x[(size_t)qi*3+2];                                            \
    xx##X = __fadd_rn(__fadd_rn(__fmul_rn(x0##X,x0##X),                   \
                                __fmul_rn(x1##X,x1##X)),                  \
                      __fmul_rn(x2##X,x2##X)); }

#define NN_STEP(X) {                                                      \
    float dot = __fadd_rn(__fadd_rn(__fmul_rn(x0##X,s.x),                 \
                                    __fmul_rn(x1##X,s.y)),                \
                          __fmul_rn(x2##X,s.z));                          \
    float d2 = __fadd_rn(__fmaf_rn(-2.0f, dot, xx##X), s.w);              \
    const float k0 = bd0##X, k1 = bd1##X, k2 = bd2##X;                    \
    const bool c0 = d2 < k0, c1 = d2 < k1, c2 = d2 < k2;                  \
    bi2##X = c1 ? bi1##X : (c2 ? m : bi2##X);                             \
    bi1##X = c0 ? bi0##X : (c1 ? m : bi1##X);                             \
    bi0##X = c0 ? m : bi0##X;                                             \
    bd0##X = fminf(k0, d2);                                               \
    bd1##X = __builtin_amdgcn_fmed3f(d2, k0, k1);                         \
    bd2##X = __builtin_amdgcn_fmed3f(d2, k1, k2); }

#define NN_STORE(X, QQ) {                                                 \
    const int qi = q0 + (QQ) * 256 + t;                                   \
    part_d[(size_t)split * NQ + qi] =                                     \
        make_float4(bd0##X, bd1##X, bd2##X, 0.f);                         \
    part_i[(size_t)split * NQ + qi] =                                     \
        make_int4(bi0##X, bi1##X, bi2##X, 0); }

__global__ __launch_bounds__(256) void nn_split_kernel(const float* __restrict__ x,
                                                       const float4* __restrict__ packed,
                                                       float4* __restrict__ part_d,
                                                       int4* __restrict__ part_i) {
    __shared__ float4 spts[MCHUNK];   // 4 KB
    const int split = blockIdx.x & (NSPLIT - 1);
    const int qb    = blockIdx.x >> 4;
    const int q0    = qb * 1024;
    const int b     = q0 >> 15;                     // N_=32768
    const int t     = threadIdx.x;

    spts[t] = packed[(size_t)b * M_ + split * MCHUNK + t];
    __syncthreads();

    NN_DECL(A) NN_DECL(B) NN_DECL(C) NN_DECL(D)
    NN_LOAD(A, 0) NN_LOAD(B, 1) NN_LOAD(C, 2) NN_LOAD(D, 3)

    const int m_base = split * MCHUNK;
    #pragma unroll 2
    for (int j = 0; j < MCHUNK; ++j) {
        const float4 s = spts[j];
        const int m = m_base + j;
        NN_STEP(A) NN_STEP(B) NN_STEP(C) NN_STEP(D)
    }

    NN_STORE(A, 0) NN_STORE(B, 1) NN_STORE(C, 2) NN_STORE(D, 3)
}

// ---------------------------------------------------------------------------
// K1b: merge 16 partial top-3s per query. Ascending-m order + strict '<' ->
// first-wins tie handling, identical to a single pass over all 4096 points.
// ---------------------------------------------------------------------------
__device__ __forceinline__ void ins3(float d, int m, float& b0, float& b1, float& b2,
                                     int& i0, int& i1, int& i2) {
    if (d < b2) {
        if (d < b1) {
            b2 = b1; i2 = i1;
            if (d < b0) { b1 = b0; i1 = i0; b0 = d; i0 = m; }
            else        { b1 = d;  i1 = m; }
        } else { b2 = d; i2 = m; }
    }
}

__global__ __launch_bounds__(256) void merge_kernel(const float4* __restrict__ part_d,
                                                    const int4* __restrict__ part_i,
                                                    int4* __restrict__ idx_out) {
    const int q = blockIdx.x * 256 + threadIdx.x;
    float b0 = 1e30f, b1 = 1e30f, b2 = 1e30f;
    int   i0 = 0,     i1 = 0,     i2 = 0;
    #pragma unroll
    for (int s = 0; s < NSPLIT; ++s) {
        float4 d = part_d[(size_t)s * NQ + q];
        int4   i = part_i[(size_t)s * NQ + q];
        ins3(d.x, i.x, b0, b1, b2, i0, i1, i2);
        ins3(d.y, i.y, b0, b1, b2, i0, i1, i2);
        ins3(d.z, i.z, b0, b1, b2, i0, i1, i2);
    }
    idx_out[q] = make_int4(i0, i1, i2, 0);
}

// ---------------------------------------------------------------------------
// K2 (fused): interp-gather + gemm1(relu, xyz-fold) + gemm2 + transposed store.
// (unchanged from R7; ~same speed as 3 separate kernels but 128MB less HBM
// traffic and 2 fewer launches)
// ---------------------------------------------------------------------------
__global__ __launch_bounds__(256) void fused_mlp_kernel(const float* __restrict__ features,
                                                        const int4* __restrict__ idx,
                                                        const float* __restrict__ x,
                                                        const float* __restrict__ w1,
                                                        const float* __restrict__ b1,
                                                        const float* __restrict__ w2,
                                                        const float* __restrict__ b2,
                                                        float* __restrict__ out) {
    __shared__ float sT[128][132];   // [k][row], 67.6 KB: I-tile, then H-tile
    __shared__ float sW[16][132];    // weight chunk [k][out], 8.4 KB
    const int row0 = blockIdx.x * 128;
    const int tid  = threadIdx.x;
    const int tr   = tid & 15;
    const int tc   = tid >> 4;
    const int b    = row0 >> 15;

    // ---- Phase 0: gather 3 neighbor rows, average, write I into sT[k][q] ----
    {
        const int q    = tid >> 1;          // query within tile [0,128)
        const int half = tid & 1;           // which 16 float4-cols
        const int4 v   = idx[row0 + q];
        const float4* fb = (const float4*)features + (size_t)b * M_ * (C_/4);
        const float4* r0 = fb + (size_t)v.x * 32;
        const float4* r1 = fb + (size_t)v.y * 32;
        const float4* r2 = fb + (size_t)v.z * 32;
        #pragma unroll
        for (int u = 0; u < 16; ++u) {
            const int c4 = half * 16 + u;
            float4 f0 = r0[c4], f1 = r1[c4], f2 = r2[c4];
            sT[c4*4+0][q] = ((f0.x + f1.x) + f2.x) / 3.0f;
            sT[c4*4+1][q] = ((f0.y + f1.y) + f2.y) / 3.0f;
            sT[c4*4+2][q] = ((f0.z + f1.z) + f2.z) / 3.0f;
            sT[c4*4+3][q] = ((f0.w + f1.w) + f2.w) / 3.0f;
        }
    }
    __syncthreads();

    // ---- Phase 1: gemm1 from sT, w1 chunks staged per-kc ----
    float acc[8][8] = {};
    for (int kc = 0; kc < 8; ++kc) {
        {
            int o = tid >> 1, kk0 = (tid & 1) * 8;
            #pragma unroll
            for (int kk = 0; kk < 8; ++kk)
                sW[kk0+kk][o] = w1[(size_t)o * IN_ + 3 + kc*16 + kk0 + kk];
        }
        __syncthreads();
        #pragma unroll
        for (int kk = 0; kk < 16; ++kk) {
            float4 a0 = *(const float4*)&sT[kc*16+kk][tr*8];
            float4 a1 = *(const float4*)&sT[kc*16+kk][tr*8+4];
            float4 c0 = *(const float4*)&sW[kk][tc*8];
            float4 c1 = *(const float4*)&sW[kk][tc*8+4];
            float av[8] = {a0.x,a0.y,a0.z,a0.w,a1.x,a1.y,a1.z,a1.w};
            float bv[8] = {c0.x,c0.y,c0.z,c0.w,c1.x,c1.y,c1.z,c1.w};
            #pragma unroll
            for (int i = 0; i < 8; ++i)
                #pragma unroll
                for (int j = 0; j < 8; ++j)
                    acc[i][j] = fmaf(av[i], bv[j], acc[i][j]);
        }
        __syncthreads();
    }

    // ---- epilogue 1: xyz columns + bias + relu (registers) ----
    {
        float wx0[8], wx1[8], wx2[8], bb[8];
        #pragma unroll
        for (int j = 0; j < 8; ++j) {
            int o = tc*8 + j;
            wx0[j] = w1[(size_t)o*IN_+0];
            wx1[j] = w1[(size_t)o*IN_+1];
            wx2[j] = w1[(size_t)o*IN_+2];
            bb[j]  = b1[o];
        }
        #pragma unroll
        for (int i = 0; i < 8; ++i) {
            int r = row0 + tr*8 + i;
            float x0 = x[(size_t)r*3+0], x1 = x[(size_t)r*3+1], x2 = x[(size_t)r*3+2];
            #pragma unroll
            for (int j = 0; j < 8; ++j) {
                float v = acc[i][j] + wx0[j]*x0 + wx1[j]*x1 + wx2[j]*x2 + bb[j];
                acc[i][j] = v > 0.0f ? v : 0.0f;
            }
        }
    }

    // ---- Phase 2: write H into sT[o][row] ----
    #pragma unroll
    for (int i = 0; i < 8; ++i)
        #pragma unroll
        for (int j = 0; j < 8; ++j)
            sT[tc*8+j][tr*8+i] = acc[i][j];
    __syncthreads();

    // ---- Phase 3: gemm2 from sT, w2 chunks staged per-kc ----
    float acc2[8][8] = {};
    for (int kc = 0; kc < 8; ++kc) {
        {
            int o = tid >> 1, kq = tid & 1;
            float4 h0 = *(const float4*)&w2[(size_t)o * OUT_ + kc*16 + kq*8];
            float4 h1 = *(const float4*)&w2[(size_t)o * OUT_ + kc*16 + kq*8 + 4];
            sW[kq*8+0][o] = h0.x; sW[kq*8+1][o] = h0.y;
            sW[kq*8+2][o] = h0.z; sW[kq*8+3][o] = h0.w;
            sW[kq*8+4][o] = h1.x; sW[kq*8+5][o] = h1.y;
            sW[kq*8+6][o] = h1.z; sW[kq*8+7][o] = h1.w;
        }
        __syncthreads();
        #pragma unroll
        for (int kk = 0; kk < 16; ++kk) {
            float4 a0 = *(const float4*)&sT[kc*16+kk][tr*8];
            float4 a1 = *(const float4*)&sT[kc*16+kk][tr*8+4];
            float4 c0 = *(const float4*)&sW[kk][tc*8];
            float4 c1 = *(const float4*)&sW[kk][tc*8+4];
            float av[8] = {a0.x,a0.y,a0.z,a0.w,a1.x,a1.y,a1.z,a1.w};
            float bv[8] = {c0.x,c0.y,c0.z,c0.w,c1.x,c1.y,c1.z,c1.w};
            #pragma unroll
            for (int i = 0; i < 8; ++i)
                #pragma unroll
                for (int j = 0; j < 8; ++j)
                    acc2[i][j] = fmaf(av[i], bv[j], acc2[i][j]);
        }
        __syncthreads();
    }

    // ---- epilogue 2: bias + transposed store out[b][o][n] ----
    const int n0 = (row0 & (N_-1)) + tr*8;
    #pragma unroll
    for (int j = 0; j < 8; ++j) {
        int o = tc*8 + j;
        float bias = b2[o];
        float4 o0 = make_float4(acc2[0][j]+bias, acc2[1][j]+bias,
                                acc2[2][j]+bias, acc2[3][j]+bias);
        float4 o1 = make_float4(acc2[4][j]+bias, acc2[5][j]+bias,
                                acc2[6][j]+bias, acc2[7][j]+bias);
        float* dst = out + (((size_t)(b*OUT_ + o)) << 15) + n0;
        *(float4*)dst       = o0;
        *(float4*)(dst + 4) = o1;
    }
}

extern "C" void kernel_launch(void* const* d_in, const int* in_sizes, int n_in,
                              void* d_out, int out_size, void* d_ws, size_t ws_size,
                              hipStream_t stream) {
    const float* x        = (const float*)d_in[0];   // [B,N,3]
    const float* sx       = (const float*)d_in[1];   // [B,M,3]
    const float* features = (const float*)d_in[2];   // [B,M,C]
    const float* w1       = (const float*)d_in[3];   // [128,131]
    const float* b1       = (const float*)d_in[4];   // [128]
    const float* w2       = (const float*)d_in[5];   // [128,128]
    const float* b2       = (const float*)d_in[6];   // [128]
    float* out = (float*)d_out;                      // [B,128,N]

    char* ws = (char*)d_ws;
    // Layout:
    //   [0,1MB)     idx      (written by merge)
    //   [1,2MB)     packed   (dead after nn_split)
    //   [33,49MB)   part_d
    //   [49,65MB)   part_i
    int4*   idxb   = (int4*)ws;
    float4* packed = (float4*)(ws + (1u  << 20));
    float4* part_d = (float4*)(ws + (33u << 20));            // 16 MB
    int4*   part_i = (int4*) (ws + (33u << 20) + (16u<<20)); // 16 MB

    pack_kernel    <<<dim3((B_*M_ + 255)/256), dim3(256), 0, stream>>>(sx, packed);
    nn_split_kernel<<<dim3((NQ/1024) * NSPLIT), dim3(256), 0, stream>>>(x, packed, part_d, part_i);
    merge_kernel   <<<dim3(NQ/256), dim3(256), 0, stream>>>(part_d, part_i, idxb);
    fused_mlp_kernel<<<dim3(NQ/128), dim3(256), 0, stream>>>(features, idxb, x,
                                                             w1, b1, w2, b2, out);
}

// Round 9
// 285.695 us; speedup vs baseline: 1.1367x; 1.0438x over previous
//
#include <hip/hip_runtime.h>

#define B_   2
#define N_   32768
#define M_   4096
#define C_   128
#define OUT_ 128
#define IN_  131

#define NSPLIT 16
#define MCHUNK (M_ / NSPLIT)     // 256 points per split
#define NQ     (B_ * N_)         // 65536 total queries

// ---------------------------------------------------------------------------
// K0: pack sampled points as (s0,s1,s2,|s|^2), reference rounding order.
// ---------------------------------------------------------------------------
__global__ __launch_bounds__(256) void pack_kernel(const float* __restrict__ sx,
                                                   float4* __restrict__ packed) {
    const int t = blockIdx.x * 256 + threadIdx.x;   // [0, B_*M_)
    if (t >= B_ * M_) return;
    float s0 = sx[3*t+0], s1 = sx[3*t+1], s2 = sx[3*t+2];
    float ss = __fadd_rn(__fadd_rn(__fmul_rn(s0,s0), __fmul_rn(s1,s1)),
                         __fmul_rn(s2,s2));
    packed[t] = make_float4(s0, s1, s2, ss);
}

// ---------------------------------------------------------------------------
// K1: split brute-force 3-NN, branchless top-3, explicit scalar state.
// (byte-identical to R8's passing kernel)
// ---------------------------------------------------------------------------
#define NN_DECL(X)                                                        \
    float x0##X, x1##X, x2##X, xx##X;                                     \
    float bd0##X = 1e30f, bd1##X = 1e30f, bd2##X = 1e30f;                 \
    int   bi0##X = 0,     bi1##X = 0,     bi2##X = 0;

#define NN_LOAD(X, QQ) {                                                  \
    const int qi = q0 + (QQ) * 256 + t;                                   \
    x0##X = x[(size_t)qi*3+0];                                            \
    x1##X = x[(size_t)qi*3+1];                                            \
    x2##X = x[(size_t)qi*3+2];                                            \
    xx##X = __fadd_rn(__fadd_rn(__fmul_rn(x0##X,x0##X),                   \
                                __fmul_rn(x1##X,x1##X)),                  \
                      __fmul_rn(x2##X,x2##X)); }

#define NN_STEP(X) {                                                      \
    float dot = __fadd_rn(__fadd_rn(__fmul_rn(x0##X,s.x),                 \
                                    __fmul_rn(x1##X,s.y)),                \
                          __fmul_rn(x2##X,s.z));                          \
    float d2 = __fadd_rn(__fmaf_rn(-2.0f, dot, xx##X), s.w);              \
    const float k0 = bd0##X, k1 = bd1##X, k2 = bd2##X;                    \
    const bool c0 = d2 < k0, c1 = d2 < k1, c2 = d2 < k2;                  \
    bi2##X = c1 ? bi1##X : (c2 ? m : bi2##X);                             \
    bi1##X = c0 ? bi0##X : (c1 ? m : bi1##X);                             \
    bi0##X = c0 ? m : bi0##X;                                             \
    bd0##X = fminf(k0, d2);                                               \
    bd1##X = __builtin_amdgcn_fmed3f(d2, k0, k1);                         \
    bd2##X = __builtin_amdgcn_fmed3f(d2, k1, k2); }

#define NN_STORE(X, QQ) {                                                 \
    const int qi = q0 + (QQ) * 256 + t;                                   \
    part_d[(size_t)split * NQ + qi] =                                     \
        make_float4(bd0##X, bd1##X, bd2##X, 0.f);                         \
    part_i[(size_t)split * NQ + qi] =                                     \
        make_int4(bi0##X, bi1##X, bi2##X, 0); }

__global__ __launch_bounds__(256) void nn_split_kernel(const float* __restrict__ x,
                                                       const float4* __restrict__ packed,
                                                       float4* __restrict__ part_d,
                                                       int4* __restrict__ part_i) {
    __shared__ float4 spts[MCHUNK];   // 4 KB
    const int split = blockIdx.x & (NSPLIT - 1);
    const int qb    = blockIdx.x >> 4;
    const int q0    = qb * 1024;
    const int b     = q0 >> 15;                     // N_=32768
    const int t     = threadIdx.x;

    spts[t] = packed[(size_t)b * M_ + split * MCHUNK + t];
    __syncthreads();

    NN_DECL(A) NN_DECL(B) NN_DECL(C) NN_DECL(D)
    NN_LOAD(A, 0) NN_LOAD(B, 1) NN_LOAD(C, 2) NN_LOAD(D, 3)

    const int m_base = split * MCHUNK;
    #pragma unroll 2
    for (int j = 0; j < MCHUNK; ++j) {
        const float4 s = spts[j];
        const int m = m_base + j;
        NN_STEP(A) NN_STEP(B) NN_STEP(C) NN_STEP(D)
    }

    NN_STORE(A, 0) NN_STORE(B, 1) NN_STORE(C, 2) NN_STORE(D, 3)
}

// ---------------------------------------------------------------------------
// K1b: merge 16 partial top-3s per query (ascending-m, strict '<').
// ---------------------------------------------------------------------------
__device__ __forceinline__ void ins3(float d, int m, float& b0, float& b1, float& b2,
                                     int& i0, int& i1, int& i2) {
    if (d < b2) {
        if (d < b1) {
            b2 = b1; i2 = i1;
            if (d < b0) { b1 = b0; i1 = i0; b0 = d; i0 = m; }
            else        { b1 = d;  i1 = m; }
        } else { b2 = d; i2 = m; }
    }
}

__global__ __launch_bounds__(256) void merge_kernel(const float4* __restrict__ part_d,
                                                    const int4* __restrict__ part_i,
                                                    int4* __restrict__ idx_out) {
    const int q = blockIdx.x * 256 + threadIdx.x;
    float b0 = 1e30f, b1 = 1e30f, b2 = 1e30f;
    int   i0 = 0,     i1 = 0,     i2 = 0;
    #pragma unroll
    for (int s = 0; s < NSPLIT; ++s) {
        float4 d = part_d[(size_t)s * NQ + q];
        int4   i = part_i[(size_t)s * NQ + q];
        ins3(d.x, i.x, b0, b1, b2, i0, i1, i2);
        ins3(d.y, i.y, b0, b1, b2, i0, i1, i2);
        ins3(d.z, i.z, b0, b1, b2, i0, i1, i2);
    }
    idx_out[q] = make_int4(i0, i1, i2, 0);
}

// ---------------------------------------------------------------------------
// K2a: G = features @ W1f^T  over all B*M sampled points (8192 x 128, K=128).
// Linearity: h = ((f0+f1+f2)/3)@W1f^T = (G[i0]+G[i1]+G[i2])/3 -- this shifts
// gemm1 from 65536 rows to 8192 rows (8x fewer FLOPs + no per-query staging).
// Same tile structure as the old gemm1, minus xyz/bias/relu.
// ---------------------------------------------------------------------------
__global__ __launch_bounds__(256) void pre_gemm_kernel(const float* __restrict__ features,
                                                       const float* __restrict__ w1,
                                                       float* __restrict__ G) {
    __shared__ float sI[16][132];
    __shared__ float sW[16][132];
    const int row0 = blockIdx.x * 128;     // over B_*M_ = 8192 rows
    const int tid  = threadIdx.x;
    const int tr   = tid & 15;
    const int tc   = tid >> 4;
    float acc[8][8] = {};

    for (int kc = 0; kc < 8; ++kc) {
        #pragma unroll
        for (int j = 0; j < 2; ++j) {
            int id  = j * 256 + tid;
            int row = id >> 2, kq = id & 3;
            float4 g = ((const float4*)features)[(size_t)(row0 + row) * 32 + kc * 4 + kq];
            sI[kq*4+0][row] = g.x; sI[kq*4+1][row] = g.y;
            sI[kq*4+2][row] = g.z; sI[kq*4+3][row] = g.w;
        }
        {
            int o = tid >> 1, kk0 = (tid & 1) * 8;
            #pragma unroll
            for (int kk = 0; kk < 8; ++kk)
                sW[kk0+kk][o] = w1[(size_t)o * IN_ + 3 + kc*16 + kk0 + kk];
        }
        __syncthreads();
        #pragma unroll
        for (int kk = 0; kk < 16; ++kk) {
            float4 a0 = *(const float4*)&sI[kk][tr*8];
            float4 a1 = *(const float4*)&sI[kk][tr*8+4];
            float4 c0 = *(const float4*)&sW[kk][tc*8];
            float4 c1 = *(const float4*)&sW[kk][tc*8+4];
            float av[8] = {a0.x,a0.y,a0.z,a0.w,a1.x,a1.y,a1.z,a1.w};
            float bv[8] = {c0.x,c0.y,c0.z,c0.w,c1.x,c1.y,c1.z,c1.w};
            #pragma unroll
            for (int i = 0; i < 8; ++i)
                #pragma unroll
                for (int j = 0; j < 8; ++j)
                    acc[i][j] = fmaf(av[i], bv[j], acc[i][j]);
        }
        __syncthreads();
    }

    #pragma unroll
    for (int i = 0; i < 8; ++i) {
        int r = row0 + tr*8 + i;
        float4 o0 = make_float4(acc[i][0], acc[i][1], acc[i][2], acc[i][3]);
        float4 o1 = make_float4(acc[i][4], acc[i][5], acc[i][6], acc[i][7]);
        ((float4*)G)[(size_t)r * 32 + tc*2 + 0] = o0;
        ((float4*)G)[(size_t)r * 32 + tc*2 + 1] = o1;
    }
}

// ---------------------------------------------------------------------------
// K2b: per 128-query tile: H = relu(gather3(G)/3 + x@W1x^T + b1) built
// directly in LDS (no gemm1!), then gemm2 from LDS, transposed store.
// ---------------------------------------------------------------------------
__global__ __launch_bounds__(256) void fused_out_kernel(const float* __restrict__ G,
                                                        const int4* __restrict__ idx,
                                                        const float* __restrict__ x,
                                                        const float* __restrict__ w1,
                                                        const float* __restrict__ b1,
                                                        const float* __restrict__ w2,
                                                        const float* __restrict__ b2,
                                                        float* __restrict__ out) {
    __shared__ float  sT[128][132];   // [o][q] H-tile, 67.6 KB
    __shared__ float  sW[16][132];    // w2 chunk [k][out], 8.4 KB
    __shared__ float4 sWX[128];       // (wx0,wx1,wx2,b1) per out channel, 2 KB
    const int row0 = blockIdx.x * 128;
    const int tid  = threadIdx.x;
    const int tr   = tid & 15;
    const int tc   = tid >> 4;
    const int b    = row0 >> 15;

    // stage xyz-weights + bias (once per block)
    if (tid < 128)
        sWX[tid] = make_float4(w1[(size_t)tid*IN_+0], w1[(size_t)tid*IN_+1],
                               w1[(size_t)tid*IN_+2], b1[tid]);
    __syncthreads();

    // ---- Phase 0: H[o][q] = relu((G0+G1+G2)/3 + wx.x + b) ----
    {
        const int q    = tid >> 1;          // query within tile [0,128)
        const int half = tid & 1;           // which 64 out-channels
        const int4 v   = idx[row0 + q];
        const float4* g0 = (const float4*)G + (size_t)(b * M_ + v.x) * 32;
        const float4* g1 = (const float4*)G + (size_t)(b * M_ + v.y) * 32;
        const float4* g2 = (const float4*)G + (size_t)(b * M_ + v.z) * 32;
        const int r = row0 + q;
        const float xr0 = x[(size_t)r*3+0];
        const float xr1 = x[(size_t)r*3+1];
        const float xr2 = x[(size_t)r*3+2];
        #pragma unroll
        for (int u = 0; u < 16; ++u) {
            const int c4 = half * 16 + u;
            float4 a = g0[c4], e = g1[c4], f = g2[c4];
            float4 w0 = sWX[c4*4+0], w1v = sWX[c4*4+1];
            float4 w2v = sWX[c4*4+2], w3 = sWX[c4*4+3];
            float h;
            h = ((a.x + e.x) + f.x) * (1.0f/3.0f);
            h = fmaf(w0.x,xr0, fmaf(w0.y,xr1, fmaf(w0.z,xr2, h))) + w0.w;
            sT[c4*4+0][q] = h > 0.0f ? h : 0.0f;
            h = ((a.y + e.y) + f.y) * (1.0f/3.0f);
            h = fmaf(w1v.x,xr0, fmaf(w1v.y,xr1, fmaf(w1v.z,xr2, h))) + w1v.w;
            sT[c4*4+1][q] = h > 0.0f ? h : 0.0f;
            h = ((a.z + e.z) + f.z) * (1.0f/3.0f);
            h = fmaf(w2v.x,xr0, fmaf(w2v.y,xr1, fmaf(w2v.z,xr2, h))) + w2v.w;
            sT[c4*4+2][q] = h > 0.0f ? h : 0.0f;
            h = ((a.w + e.w) + f.w) * (1.0f/3.0f);
            h = fmaf(w3.x,xr0, fmaf(w3.y,xr1, fmaf(w3.z,xr2, h))) + w3.w;
            sT[c4*4+3][q] = h > 0.0f ? h : 0.0f;
        }
    }
    __syncthreads();

    // ---- Phase 1: gemm2 from sT, w2 chunks staged per-kc ----
    float acc2[8][8] = {};
    for (int kc = 0; kc < 8; ++kc) {
        {
            int o = tid >> 1, kq = tid & 1;
            float4 h0 = *(const float4*)&w2[(size_t)o * OUT_ + kc*16 + kq*8];
            float4 h1 = *(const float4*)&w2[(size_t)o * OUT_ + kc*16 + kq*8 + 4];
            sW[kq*8+0][o] = h0.x; sW[kq*8+1][o] = h0.y;
            sW[kq*8+2][o] = h0.z; sW[kq*8+3][o] = h0.w;
            sW[kq*8+4][o] = h1.x; sW[kq*8+5][o] = h1.y;
            sW[kq*8+6][o] = h1.z; sW[kq*8+7][o] = h1.w;
        }
        __syncthreads();
        #pragma unroll
        for (int kk = 0; kk < 16; ++kk) {
            float4 a0 = *(const float4*)&sT[kc*16+kk][tr*8];
            float4 a1 = *(const float4*)&sT[kc*16+kk][tr*8+4];
            float4 c0 = *(const float4*)&sW[kk][tc*8];
            float4 c1 = *(const float4*)&sW[kk][tc*8+4];
            float av[8] = {a0.x,a0.y,a0.z,a0.w,a1.x,a1.y,a1.z,a1.w};
            float bv[8] = {c0.x,c0.y,c0.z,c0.w,c1.x,c1.y,c1.z,c1.w};
            #pragma unroll
            for (int i = 0; i < 8; ++i)
                #pragma unroll
                for (int j = 0; j < 8; ++j)
                    acc2[i][j] = fmaf(av[i], bv[j], acc2[i][j]);
        }
        __syncthreads();
    }

    // ---- epilogue: bias + transposed store out[b][o][n] ----
    const int n0 = (row0 & (N_-1)) + tr*8;
    #pragma unroll
    for (int j = 0; j < 8; ++j) {
        int o = tc*8 + j;
        float bias = b2[o];
        float4 o0 = make_float4(acc2[0][j]+bias, acc2[1][j]+bias,
                                acc2[2][j]+bias, acc2[3][j]+bias);
        float4 o1 = make_float4(acc2[4][j]+bias, acc2[5][j]+bias,
                                acc2[6][j]+bias, acc2[7][j]+bias);
        float* dst = out + (((size_t)(b*OUT_ + o)) << 15) + n0;
        *(float4*)dst       = o0;
        *(float4*)(dst + 4) = o1;
    }
}

extern "C" void kernel_launch(void* const* d_in, const int* in_sizes, int n_in,
                              void* d_out, int out_size, void* d_ws, size_t ws_size,
                              hipStream_t stream) {
    const float* x        = (const float*)d_in[0];   // [B,N,3]
    const float* sx       = (const float*)d_in[1];   // [B,M,3]
    const float* features = (const float*)d_in[2];   // [B,M,C]
    const float* w1       = (const float*)d_in[3];   // [128,131]
    const float* b1       = (const float*)d_in[4];   // [128]
    const float* w2       = (const float*)d_in[5];   // [128,128]
    const float* b2       = (const float*)d_in[6];   // [128]
    float* out = (float*)d_out;                      // [B,128,N]

    char* ws = (char*)d_ws;
    // Layout:
    //   [0,1MB)     idx
    //   [1,2MB)     packed  (dead after nn_split)
    //   [2,6MB)     G       (4 MB, features @ W1f^T)
    //   [33,49MB)   part_d
    //   [49,65MB)   part_i
    int4*   idxb   = (int4*)ws;
    float4* packed = (float4*)(ws + (1u  << 20));
    float*  G      = (float*)(ws + (2u  << 20));
    float4* part_d = (float4*)(ws + (33u << 20));
    int4*   part_i = (int4*) (ws + (33u << 20) + (16u<<20));

    pack_kernel    <<<dim3((B_*M_ + 255)/256), dim3(256), 0, stream>>>(sx, packed);
    nn_split_kernel<<<dim3((NQ/1024) * NSPLIT), dim3(256), 0, stream>>>(x, packed, part_d, part_i);
    merge_kernel   <<<dim3(NQ/256), dim3(256), 0, stream>>>(part_d, part_i, idxb);
    pre_gemm_kernel<<<dim3(B_*M_/128), dim3(256), 0, stream>>>(features, w1, G);
    fused_out_kernel<<<dim3(NQ/128), dim3(256), 0, stream>>>(G, idxb, x,
                                                             w1, b1, w2, b2, out);
}

// Round 10
// 275.511 us; speedup vs baseline: 1.1788x; 1.0370x over previous
//
#include <hip/hip_runtime.h>

#define B_   2
#define N_   32768
#define M_   4096
#define C_   128
#define OUT_ 128
#define IN_  131

#define NSPLIT 16
#define MCHUNK (M_ / NSPLIT)     // 256 points per split
#define NQ     (B_ * N_)         // 65536 total queries

// ---------------------------------------------------------------------------
// K0: pack sampled points as (s0,s1,s2,|s|^2), reference rounding order.
// ---------------------------------------------------------------------------
__global__ __launch_bounds__(256) void pack_kernel(const float* __restrict__ sx,
                                                   float4* __restrict__ packed) {
    const int t = blockIdx.x * 256 + threadIdx.x;   // [0, B_*M_)
    if (t >= B_ * M_) return;
    float s0 = sx[3*t+0], s1 = sx[3*t+1], s2 = sx[3*t+2];
    float ss = __fadd_rn(__fadd_rn(__fmul_rn(s0,s0), __fmul_rn(s1,s1)),
                         __fmul_rn(s2,s2));
    packed[t] = make_float4(s0, s1, s2, ss);
}

// ---------------------------------------------------------------------------
// K1: split brute-force 3-NN, branchless top-3, explicit scalar state.
// (byte-identical to R8/R9's passing kernel)
// ---------------------------------------------------------------------------
#define NN_DECL(X)                                                        \
    float x0##X, x1##X, x2##X, xx##X;                                     \
    float bd0##X = 1e30f, bd1##X = 1e30f, bd2##X = 1e30f;                 \
    int   bi0##X = 0,     bi1##X = 0,     bi2##X = 0;

#define NN_LOAD(X, QQ) {                                                  \
    const int qi = q0 + (QQ) * 256 + t;                                   \
    x0##X = x[(size_t)qi*3+0];                                            \
    x1##X = x[(size_t)qi*3+1];                                            \
    x2##X = x[(size_t)qi*3+2];                                            \
    xx##X = __fadd_rn(__fadd_rn(__fmul_rn(x0##X,x0##X),                   \
                                __fmul_rn(x1##X,x1##X)),                  \
                      __fmul_rn(x2##X,x2##X)); }

#define NN_STEP(X) {                                                      \
    float dot = __fadd_rn(__fadd_rn(__fmul_rn(x0##X,s.x),                 \
                                    __fmul_rn(x1##X,s.y)),                \
                          __fmul_rn(x2##X,s.z));                          \
    float d2 = __fadd_rn(__fmaf_rn(-2.0f, dot, xx##X), s.w);              \
    const float k0 = bd0##X, k1 = bd1##X, k2 = bd2##X;                    \
    const bool c0 = d2 < k0, c1 = d2 < k1, c2 = d2 < k2;                  \
    bi2##X = c1 ? bi1##X : (c2 ? m : bi2##X);                             \
    bi1##X = c0 ? bi0##X : (c1 ? m : bi1##X);                             \
    bi0##X = c0 ? m : bi0##X;                                             \
    bd0##X = fminf(k0, d2);                                               \
    bd1##X = __builtin_amdgcn_fmed3f(d2, k0, k1);                         \
    bd2##X = __builtin_amdgcn_fmed3f(d2, k1, k2); }

#define NN_STORE(X, QQ) {                                                 \
    const int qi = q0 + (QQ) * 256 + t;                                   \
    part_d[(size_t)split * NQ + qi] =                                     \
        make_float4(bd0##X, bd1##X, bd2##X, 0.f);                         \
    part_i[(size_t)split * NQ + qi] =                                     \
        make_int4(bi0##X, bi1##X, bi2##X, 0); }

__global__ __launch_bounds__(256) void nn_split_kernel(const float* __restrict__ x,
                                                       const float4* __restrict__ packed,
                                                       float4* __restrict__ part_d,
                                                       int4* __restrict__ part_i) {
    __shared__ float4 spts[MCHUNK];   // 4 KB
    const int split = blockIdx.x & (NSPLIT - 1);
    const int qb    = blockIdx.x >> 4;
    const int q0    = qb * 1024;
    const int b     = q0 >> 15;                     // N_=32768
    const int t     = threadIdx.x;

    spts[t] = packed[(size_t)b * M_ + split * MCHUNK + t];
    __syncthreads();

    NN_DECL(A) NN_DECL(B) NN_DECL(C) NN_DECL(D)
    NN_LOAD(A, 0) NN_LOAD(B, 1) NN_LOAD(C, 2) NN_LOAD(D, 3)

    const int m_base = split * MCHUNK;
    #pragma unroll 2
    for (int j = 0; j < MCHUNK; ++j) {
        const float4 s = spts[j];
        const int m = m_base + j;
        NN_STEP(A) NN_STEP(B) NN_STEP(C) NN_STEP(D)
    }

    NN_STORE(A, 0) NN_STORE(B, 1) NN_STORE(C, 2) NN_STORE(D, 3)
}

// ---------------------------------------------------------------------------
// K1b: merge 16 partial top-3s per query (ascending-m, strict '<').
// ---------------------------------------------------------------------------
__device__ __forceinline__ void ins3(float d, int m, float& b0, float& b1, float& b2,
                                     int& i0, int& i1, int& i2) {
    if (d < b2) {
        if (d < b1) {
            b2 = b1; i2 = i1;
            if (d < b0) { b1 = b0; i1 = i0; b0 = d; i0 = m; }
            else        { b1 = d;  i1 = m; }
        } else { b2 = d; i2 = m; }
    }
}

__global__ __launch_bounds__(256) void merge_kernel(const float4* __restrict__ part_d,
                                                    const int4* __restrict__ part_i,
                                                    int4* __restrict__ idx_out) {
    const int q = blockIdx.x * 256 + threadIdx.x;
    float b0 = 1e30f, b1 = 1e30f, b2 = 1e30f;
    int   i0 = 0,     i1 = 0,     i2 = 0;
    #pragma unroll
    for (int s = 0; s < NSPLIT; ++s) {
        float4 d = part_d[(size_t)s * NQ + q];
        int4   i = part_i[(size_t)s * NQ + q];
        ins3(d.x, i.x, b0, b1, b2, i0, i1, i2);
        ins3(d.y, i.y, b0, b1, b2, i0, i1, i2);
        ins3(d.z, i.z, b0, b1, b2, i0, i1, i2);
    }
    idx_out[q] = make_int4(i0, i1, i2, 0);
}

// ---------------------------------------------------------------------------
// K2a: G = features @ W1f^T over all B*M sampled points (8192 rows, K=128).
// (unchanged from R9)
// ---------------------------------------------------------------------------
__global__ __launch_bounds__(256) void pre_gemm_kernel(const float* __restrict__ features,
                                                       const float* __restrict__ w1,
                                                       float* __restrict__ G) {
    __shared__ float sI[16][132];
    __shared__ float sW[16][132];
    const int row0 = blockIdx.x * 128;
    const int tid  = threadIdx.x;
    const int tr   = tid & 15;
    const int tc   = tid >> 4;
    float acc[8][8] = {};

    for (int kc = 0; kc < 8; ++kc) {
        #pragma unroll
        for (int j = 0; j < 2; ++j) {
            int id  = j * 256 + tid;
            int row = id >> 2, kq = id & 3;
            float4 g = ((const float4*)features)[(size_t)(row0 + row) * 32 + kc * 4 + kq];
            sI[kq*4+0][row] = g.x; sI[kq*4+1][row] = g.y;
            sI[kq*4+2][row] = g.z; sI[kq*4+3][row] = g.w;
        }
        {
            int o = tid >> 1, kk0 = (tid & 1) * 8;
            #pragma unroll
            for (int kk = 0; kk < 8; ++kk)
                sW[kk0+kk][o] = w1[(size_t)o * IN_ + 3 + kc*16 + kk0 + kk];
        }
        __syncthreads();
        #pragma unroll
        for (int kk = 0; kk < 16; ++kk) {
            float4 a0 = *(const float4*)&sI[kk][tr*8];
            float4 a1 = *(const float4*)&sI[kk][tr*8+4];
            float4 c0 = *(const float4*)&sW[kk][tc*8];
            float4 c1 = *(const float4*)&sW[kk][tc*8+4];
            float av[8] = {a0.x,a0.y,a0.z,a0.w,a1.x,a1.y,a1.z,a1.w};
            float bv[8] = {c0.x,c0.y,c0.z,c0.w,c1.x,c1.y,c1.z,c1.w};
            #pragma unroll
            for (int i = 0; i < 8; ++i)
                #pragma unroll
                for (int j = 0; j < 8; ++j)
                    acc[i][j] = fmaf(av[i], bv[j], acc[i][j]);
        }
        __syncthreads();
    }

    #pragma unroll
    for (int i = 0; i < 8; ++i) {
        int r = row0 + tr*8 + i;
        float4 o0 = make_float4(acc[i][0], acc[i][1], acc[i][2], acc[i][3]);
        float4 o1 = make_float4(acc[i][4], acc[i][5], acc[i][6], acc[i][7]);
        ((float4*)G)[(size_t)r * 32 + tc*2 + 0] = o0;
        ((float4*)G)[(size_t)r * 32 + tc*2 + 1] = o1;
    }
}

// ---------------------------------------------------------------------------
// K2b: H-build (streaming, interp-style, 2KB LDS -> high occupancy):
// H[q][o] = relu((G[i0]+G[i1]+G[i2])/3 + x@W1x^T + b1). 32 lanes/query.
// R9 lesson: the 78KB-LDS fused kernel ran at 2 blocks/CU, ~5x over its
// cycle model on stalls. De-fuse; keep LDS small.
// ---------------------------------------------------------------------------
__global__ __launch_bounds__(256) void hbuild_kernel(const float* __restrict__ G,
                                                     const int4* __restrict__ idx,
                                                     const float* __restrict__ x,
                                                     const float* __restrict__ w1,
                                                     const float* __restrict__ b1,
                                                     float4* __restrict__ H) {
    __shared__ float4 sWX[128];   // (wx0,wx1,wx2,b1) per out channel, 2 KB
    const int tid  = threadIdx.x;
    if (tid < 128)
        sWX[tid] = make_float4(w1[(size_t)tid*IN_+0], w1[(size_t)tid*IN_+1],
                               w1[(size_t)tid*IN_+2], b1[tid]);
    __syncthreads();

    const int qi   = blockIdx.x * 8 + (tid >> 5);
    const int lane = tid & 31;
    const int b    = qi >> 15;
    const int4 v   = idx[qi];
    const float4* gb = (const float4*)G + (size_t)b * M_ * 32;
    float4 a = gb[(size_t)v.x * 32 + lane];
    float4 e = gb[(size_t)v.y * 32 + lane];
    float4 f = gb[(size_t)v.z * 32 + lane];
    const float xr0 = x[(size_t)qi*3+0];
    const float xr1 = x[(size_t)qi*3+1];
    const float xr2 = x[(size_t)qi*3+2];
    float4 w0  = sWX[lane*4+0], w1v = sWX[lane*4+1];
    float4 w2v = sWX[lane*4+2], w3  = sWX[lane*4+3];
    float4 r; float h;
    h = ((a.x + e.x) + f.x) * (1.0f/3.0f);
    h = fmaf(w0.x,xr0, fmaf(w0.y,xr1, fmaf(w0.z,xr2, h))) + w0.w;
    r.x = h > 0.0f ? h : 0.0f;
    h = ((a.y + e.y) + f.y) * (1.0f/3.0f);
    h = fmaf(w1v.x,xr0, fmaf(w1v.y,xr1, fmaf(w1v.z,xr2, h))) + w1v.w;
    r.y = h > 0.0f ? h : 0.0f;
    h = ((a.z + e.z) + f.z) * (1.0f/3.0f);
    h = fmaf(w2v.x,xr0, fmaf(w2v.y,xr1, fmaf(w2v.z,xr2, h))) + w2v.w;
    r.z = h > 0.0f ? h : 0.0f;
    h = ((a.w + e.w) + f.w) * (1.0f/3.0f);
    h = fmaf(w3.x,xr0, fmaf(w3.y,xr1, fmaf(w3.z,xr2, h))) + w3.w;
    r.w = h > 0.0f ? h : 0.0f;
    H[(size_t)qi * 32 + lane] = r;
}

// ---------------------------------------------------------------------------
// K3: Out[b][o][n] = H @ W2^T + b2, transposed store. Byte-copy of R1's
// proven gemm2 (16.9 KB LDS -> ~8 blocks/CU), input renamed A->H.
// ---------------------------------------------------------------------------
__global__ __launch_bounds__(256) void gemm2_kernel(const float* __restrict__ H,
                                                    const float* __restrict__ w2,
                                                    const float* __restrict__ b2,
                                                    float* __restrict__ out) {
    __shared__ float sA[16][132];
    __shared__ float sW[16][132];
    const int row0 = blockIdx.x * 128;
    const int tid  = threadIdx.x;
    const int tr   = tid & 15;
    const int tc   = tid >> 4;
    float acc[8][8] = {};

    for (int kc = 0; kc < 8; ++kc) {
        #pragma unroll
        for (int j = 0; j < 2; ++j) {
            int id  = j * 256 + tid;
            int row = id >> 2, kq = id & 3;
            float4 g = ((const float4*)H)[(size_t)(row0 + row) * 32 + kc * 4 + kq];
            sA[kq*4+0][row] = g.x; sA[kq*4+1][row] = g.y;
            sA[kq*4+2][row] = g.z; sA[kq*4+3][row] = g.w;
            float4 h = ((const float4*)w2)[(size_t)row * 32 + kc * 4 + kq];
            sW[kq*4+0][row] = h.x; sW[kq*4+1][row] = h.y;
            sW[kq*4+2][row] = h.z; sW[kq*4+3][row] = h.w;
        }
        __syncthreads();
        #pragma unroll
        for (int kk = 0; kk < 16; ++kk) {
            float4 a0 = *(const float4*)&sA[kk][tr*8];
            float4 a1 = *(const float4*)&sA[kk][tr*8+4];
            float4 c0 = *(const float4*)&sW[kk][tc*8];
            float4 c1 = *(const float4*)&sW[kk][tc*8+4];
            float av[8] = {a0.x,a0.y,a0.z,a0.w,a1.x,a1.y,a1.z,a1.w};
            float bv[8] = {c0.x,c0.y,c0.z,c0.w,c1.x,c1.y,c1.z,c1.w};
            #pragma unroll
            for (int i = 0; i < 8; ++i)
                #pragma unroll
                for (int j = 0; j < 8; ++j)
                    acc[i][j] = fmaf(av[i], bv[j], acc[i][j]);
        }
        __syncthreads();
    }

    const int b  = row0 >> 15;
    const int n0 = (row0 & (N_-1)) + tr*8;
    #pragma unroll
    for (int j = 0; j < 8; ++j) {
        int o = tc*8 + j;
        float bias = b2[o];
        float4 o0 = make_float4(acc[0][j]+bias, acc[1][j]+bias,
                                acc[2][j]+bias, acc[3][j]+bias);
        float4 o1 = make_float4(acc[4][j]+bias, acc[5][j]+bias,
                                acc[6][j]+bias, acc[7][j]+bias);
        float* dst = out + (((size_t)(b*OUT_ + o)) << 15) + n0;
        *(float4*)dst       = o0;
        *(float4*)(dst + 4) = o1;
    }
}

extern "C" void kernel_launch(void* const* d_in, const int* in_sizes, int n_in,
                              void* d_out, int out_size, void* d_ws, size_t ws_size,
                              hipStream_t stream) {
    const float* x        = (const float*)d_in[0];   // [B,N,3]
    const float* sx       = (const float*)d_in[1];   // [B,M,3]
    const float* features = (const float*)d_in[2];   // [B,M,C]
    const float* w1       = (const float*)d_in[3];   // [128,131]
    const float* b1       = (const float*)d_in[4];   // [128]
    const float* w2       = (const float*)d_in[5];   // [128,128]
    const float* b2       = (const float*)d_in[6];   // [128]
    float* out = (float*)d_out;                      // [B,128,N]

    char* ws = (char*)d_ws;
    // Layout:
    //   [0,1MB)     idx
    //   [1,2MB)     packed   (dead after nn_split)
    //   [2,6MB)     G        (4 MB)
    //   [6,38MB)    H        (32 MB; overlaps part_d/part_i tails, which are
    //                         dead after merge — hbuild runs after merge)
    //   [33,49MB)   part_d   (dead after merge)
    //   [49,65MB)   part_i   (dead after merge)
    int4*   idxb   = (int4*)ws;
    float4* packed = (float4*)(ws + (1u  << 20));
    float*  G      = (float*)(ws + (2u  << 20));
    float*  Hbuf   = (float*)(ws + (6u  << 20));
    float4* part_d = (float4*)(ws + (33u << 20));
    int4*   part_i = (int4*) (ws + (33u << 20) + (16u<<20));

    pack_kernel    <<<dim3((B_*M_ + 255)/256), dim3(256), 0, stream>>>(sx, packed);
    nn_split_kernel<<<dim3((NQ/1024) * NSPLIT), dim3(256), 0, stream>>>(x, packed, part_d, part_i);
    merge_kernel   <<<dim3(NQ/256), dim3(256), 0, stream>>>(part_d, part_i, idxb);
    pre_gemm_kernel<<<dim3(B_*M_/128), dim3(256), 0, stream>>>(features, w1, G);
    hbuild_kernel  <<<dim3(NQ/8), dim3(256), 0, stream>>>(G, idxb, x, w1, b1, (float4*)Hbuf);
    gemm2_kernel   <<<dim3(NQ/128), dim3(256), 0, stream>>>(Hbuf, w2, b2, out);
}

// Round 11
// 274.819 us; speedup vs baseline: 1.1817x; 1.0025x over previous
//
#include <hip/hip_runtime.h>

#define B_   2
#define N_   32768
#define M_   4096
#define C_   128
#define OUT_ 128
#define IN_  131

#define NSPLIT 16
#define MCHUNK (M_ / NSPLIT)     // 256 points per split
#define NQ     (B_ * N_)         // 65536 total queries

// ---------------------------------------------------------------------------
// K1: split brute-force 3-NN, branchless top-3, explicit scalar state.
// R11: __launch_bounds__(256,4) relaxes the VGPR cap (32 -> 128): R8-R10
// showed VGPR_Count=32 < ~50 live values -> allocator parked state in AGPRs
// (v_accvgpr shuffles = the ~17 phantom insts/pair over the 18-inst source
// body). 4 blocks/CU exactly matches the 1024-block grid on 256 CUs.
// Pack step (|s|^2, reference rounding order) inlined into the LDS staging.
// ---------------------------------------------------------------------------
#define NN_DECL(X)                                                        \
    float x0##X, x1##X, x2##X, xx##X;                                     \
    float bd0##X = 1e30f, bd1##X = 1e30f, bd2##X = 1e30f;                 \
    int   bi0##X = 0,     bi1##X = 0,     bi2##X = 0;

#define NN_LOAD(X, QQ) {                                                  \
    const int qi = q0 + (QQ) * 256 + t;                                   \
    x0##X = x[(size_t)qi*3+0];                                            \
    x1##X = x[(size_t)qi*3+1];                                            \
    x2##X = x[(size_t)qi*3+2];                                            \
    xx##X = __fadd_rn(__fadd_rn(__fmul_rn(x0##X,x0##X),                   \
                                __fmul_rn(x1##X,x1##X)),                  \
                      __fmul_rn(x2##X,x2##X)); }

#define NN_STEP(X) {                                                      \
    float dot = __fadd_rn(__fadd_rn(__fmul_rn(x0##X,s.x),                 \
                                    __fmul_rn(x1##X,s.y)),                \
                          __fmul_rn(x2##X,s.z));                          \
    float d2 = __fadd_rn(__fmaf_rn(-2.0f, dot, xx##X), s.w);              \
    const float k0 = bd0##X, k1 = bd1##X, k2 = bd2##X;                    \
    const bool c0 = d2 < k0, c1 = d2 < k1, c2 = d2 < k2;                  \
    bi2##X = c1 ? bi1##X : (c2 ? m : bi2##X);                             \
    bi1##X = c0 ? bi0##X : (c1 ? m : bi1##X);                             \
    bi0##X = c0 ? m : bi0##X;                                             \
    bd0##X = fminf(k0, d2);                                               \
    bd1##X = __builtin_amdgcn_fmed3f(d2, k0, k1);                         \
    bd2##X = __builtin_amdgcn_fmed3f(d2, k1, k2); }

#define NN_STORE(X, QQ) {                                                 \
    const int qi = q0 + (QQ) * 256 + t;                                   \
    part_d[(size_t)split * NQ + qi] =                                     \
        make_float4(bd0##X, bd1##X, bd2##X, 0.f);                         \
    part_i[(size_t)split * NQ + qi] =                                     \
        make_int4(bi0##X, bi1##X, bi2##X, 0); }

__global__ __launch_bounds__(256, 4) void nn_split_kernel(const float* __restrict__ x,
                                                          const float* __restrict__ sx,
                                                          float4* __restrict__ part_d,
                                                          int4* __restrict__ part_i) {
    __shared__ float4 spts[MCHUNK];   // 4 KB
    const int split = blockIdx.x & (NSPLIT - 1);
    const int qb    = blockIdx.x >> 4;
    const int q0    = qb * 1024;
    const int b     = q0 >> 15;                     // N_=32768
    const int t     = threadIdx.x;

    // stage + pack this split's points (|s|^2 in reference rounding order)
    {
        const float* sp = sx + ((size_t)b * M_ + split * MCHUNK + t) * 3;
        float s0 = sp[0], s1 = sp[1], s2 = sp[2];
        float ss = __fadd_rn(__fadd_rn(__fmul_rn(s0,s0), __fmul_rn(s1,s1)),
                             __fmul_rn(s2,s2));
        spts[t] = make_float4(s0, s1, s2, ss);
    }
    __syncthreads();

    NN_DECL(A) NN_DECL(B) NN_DECL(C) NN_DECL(D)
    NN_LOAD(A, 0) NN_LOAD(B, 1) NN_LOAD(C, 2) NN_LOAD(D, 3)

    const int m_base = split * MCHUNK;
    #pragma unroll 2
    for (int j = 0; j < MCHUNK; ++j) {
        const float4 s = spts[j];
        const int m = m_base + j;
        NN_STEP(A) NN_STEP(B) NN_STEP(C) NN_STEP(D)
    }

    NN_STORE(A, 0) NN_STORE(B, 1) NN_STORE(C, 2) NN_STORE(D, 3)
}

// ---------------------------------------------------------------------------
// K1b: merge 16 partial top-3s per query (ascending-m, strict '<').
// ---------------------------------------------------------------------------
__device__ __forceinline__ void ins3(float d, int m, float& b0, float& b1, float& b2,
                                     int& i0, int& i1, int& i2) {
    if (d < b2) {
        if (d < b1) {
            b2 = b1; i2 = i1;
            if (d < b0) { b1 = b0; i1 = i0; b0 = d; i0 = m; }
            else        { b1 = d;  i1 = m; }
        } else { b2 = d; i2 = m; }
    }
}

__global__ __launch_bounds__(256) void merge_kernel(const float4* __restrict__ part_d,
                                                    const int4* __restrict__ part_i,
                                                    int4* __restrict__ idx_out) {
    const int q = blockIdx.x * 256 + threadIdx.x;
    float b0 = 1e30f, b1 = 1e30f, b2 = 1e30f;
    int   i0 = 0,     i1 = 0,     i2 = 0;
    #pragma unroll
    for (int s = 0; s < NSPLIT; ++s) {
        float4 d = part_d[(size_t)s * NQ + q];
        int4   i = part_i[(size_t)s * NQ + q];
        ins3(d.x, i.x, b0, b1, b2, i0, i1, i2);
        ins3(d.y, i.y, b0, b1, b2, i0, i1, i2);
        ins3(d.z, i.z, b0, b1, b2, i0, i1, i2);
    }
    idx_out[q] = make_int4(i0, i1, i2, 0);
}

// ---------------------------------------------------------------------------
// K2a: G = features @ W1f^T over all B*M sampled points (8192 rows, K=128).
// ---------------------------------------------------------------------------
__global__ __launch_bounds__(256) void pre_gemm_kernel(const float* __restrict__ features,
                                                       const float* __restrict__ w1,
                                                       float* __restrict__ G) {
    __shared__ float sI[16][132];
    __shared__ float sW[16][132];
    const int row0 = blockIdx.x * 128;
    const int tid  = threadIdx.x;
    const int tr   = tid & 15;
    const int tc   = tid >> 4;
    float acc[8][8] = {};

    for (int kc = 0; kc < 8; ++kc) {
        #pragma unroll
        for (int j = 0; j < 2; ++j) {
            int id  = j * 256 + tid;
            int row = id >> 2, kq = id & 3;
            float4 g = ((const float4*)features)[(size_t)(row0 + row) * 32 + kc * 4 + kq];
            sI[kq*4+0][row] = g.x; sI[kq*4+1][row] = g.y;
            sI[kq*4+2][row] = g.z; sI[kq*4+3][row] = g.w;
        }
        {
            int o = tid >> 1, kk0 = (tid & 1) * 8;
            #pragma unroll
            for (int kk = 0; kk < 8; ++kk)
                sW[kk0+kk][o] = w1[(size_t)o * IN_ + 3 + kc*16 + kk0 + kk];
        }
        __syncthreads();
        #pragma unroll
        for (int kk = 0; kk < 16; ++kk) {
            float4 a0 = *(const float4*)&sI[kk][tr*8];
            float4 a1 = *(const float4*)&sI[kk][tr*8+4];
            float4 c0 = *(const float4*)&sW[kk][tc*8];
            float4 c1 = *(const float4*)&sW[kk][tc*8+4];
            float av[8] = {a0.x,a0.y,a0.z,a0.w,a1.x,a1.y,a1.z,a1.w};
            float bv[8] = {c0.x,c0.y,c0.z,c0.w,c1.x,c1.y,c1.z,c1.w};
            #pragma unroll
            for (int i = 0; i < 8; ++i)
                #pragma unroll
                for (int j = 0; j < 8; ++j)
                    acc[i][j] = fmaf(av[i], bv[j], acc[i][j]);
        }
        __syncthreads();
    }

    #pragma unroll
    for (int i = 0; i < 8; ++i) {
        int r = row0 + tr*8 + i;
        float4 o0 = make_float4(acc[i][0], acc[i][1], acc[i][2], acc[i][3]);
        float4 o1 = make_float4(acc[i][4], acc[i][5], acc[i][6], acc[i][7]);
        ((float4*)G)[(size_t)r * 32 + tc*2 + 0] = o0;
        ((float4*)G)[(size_t)r * 32 + tc*2 + 1] = o1;
    }
}

// ---------------------------------------------------------------------------
// K2b: H-build (streaming, 2KB LDS, high occupancy):
// H[q][o] = relu((G[i0]+G[i1]+G[i2])/3 + x@W1x^T + b1). 32 lanes/query.
// ---------------------------------------------------------------------------
__global__ __launch_bounds__(256) void hbuild_kernel(const float* __restrict__ G,
                                                     const int4* __restrict__ idx,
                                                     const float* __restrict__ x,
                                                     const float* __restrict__ w1,
                                                     const float* __restrict__ b1,
                                                     float4* __restrict__ H) {
    __shared__ float4 sWX[128];   // (wx0,wx1,wx2,b1) per out channel, 2 KB
    const int tid  = threadIdx.x;
    if (tid < 128)
        sWX[tid] = make_float4(w1[(size_t)tid*IN_+0], w1[(size_t)tid*IN_+1],
                               w1[(size_t)tid*IN_+2], b1[tid]);
    __syncthreads();

    const int qi   = blockIdx.x * 8 + (tid >> 5);
    const int lane = tid & 31;
    const int b    = qi >> 15;
    const int4 v   = idx[qi];
    const float4* gb = (const float4*)G + (size_t)b * M_ * 32;
    float4 a = gb[(size_t)v.x * 32 + lane];
    float4 e = gb[(size_t)v.y * 32 + lane];
    float4 f = gb[(size_t)v.z * 32 + lane];
    const float xr0 = x[(size_t)qi*3+0];
    const float xr1 = x[(size_t)qi*3+1];
    const float xr2 = x[(size_t)qi*3+2];
    float4 w0  = sWX[lane*4+0], w1v = sWX[lane*4+1];
    float4 w2v = sWX[lane*4+2], w3  = sWX[lane*4+3];
    float4 r; float h;
    h = ((a.x + e.x) + f.x) * (1.0f/3.0f);
    h = fmaf(w0.x,xr0, fmaf(w0.y,xr1, fmaf(w0.z,xr2, h))) + w0.w;
    r.x = h > 0.0f ? h : 0.0f;
    h = ((a.y + e.y) + f.y) * (1.0f/3.0f);
    h = fmaf(w1v.x,xr0, fmaf(w1v.y,xr1, fmaf(w1v.z,xr2, h))) + w1v.w;
    r.y = h > 0.0f ? h : 0.0f;
    h = ((a.z + e.z) + f.z) * (1.0f/3.0f);
    h = fmaf(w2v.x,xr0, fmaf(w2v.y,xr1, fmaf(w2v.z,xr2, h))) + w2v.w;
    r.z = h > 0.0f ? h : 0.0f;
    h = ((a.w + e.w) + f.w) * (1.0f/3.0f);
    h = fmaf(w3.x,xr0, fmaf(w3.y,xr1, fmaf(w3.z,xr2, h))) + w3.w;
    r.w = h > 0.0f ? h : 0.0f;
    H[(size_t)qi * 32 + lane] = r;
}

// ---------------------------------------------------------------------------
// K3: Out[b][o][n] = H @ W2^T + b2, transposed store (R1's proven gemm2).
// ---------------------------------------------------------------------------
__global__ __launch_bounds__(256) void gemm2_kernel(const float* __restrict__ H,
                                                    const float* __restrict__ w2,
                                                    const float* __restrict__ b2,
                                                    float* __restrict__ out) {
    __shared__ float sA[16][132];
    __shared__ float sW[16][132];
    const int row0 = blockIdx.x * 128;
    const int tid  = threadIdx.x;
    const int tr   = tid & 15;
    const int tc   = tid >> 4;
    float acc[8][8] = {};

    for (int kc = 0; kc < 8; ++kc) {
        #pragma unroll
        for (int j = 0; j < 2; ++j) {
            int id  = j * 256 + tid;
            int row = id >> 2, kq = id & 3;
            float4 g = ((const float4*)H)[(size_t)(row0 + row) * 32 + kc * 4 + kq];
            sA[kq*4+0][row] = g.x; sA[kq*4+1][row] = g.y;
            sA[kq*4+2][row] = g.z; sA[kq*4+3][row] = g.w;
            float4 h = ((const float4*)w2)[(size_t)row * 32 + kc * 4 + kq];
            sW[kq*4+0][row] = h.x; sW[kq*4+1][row] = h.y;
            sW[kq*4+2][row] = h.z; sW[kq*4+3][row] = h.w;
        }
        __syncthreads();
        #pragma unroll
        for (int kk = 0; kk < 16; ++kk) {
            float4 a0 = *(const float4*)&sA[kk][tr*8];
            float4 a1 = *(const float4*)&sA[kk][tr*8+4];
            float4 c0 = *(const float4*)&sW[kk][tc*8];
            float4 c1 = *(const float4*)&sW[kk][tc*8+4];
            float av[8] = {a0.x,a0.y,a0.z,a0.w,a1.x,a1.y,a1.z,a1.w};
            float bv[8] = {c0.x,c0.y,c0.z,c0.w,c1.x,c1.y,c1.z,c1.w};
            #pragma unroll
            for (int i = 0; i < 8; ++i)
                #pragma unroll
                for (int j = 0; j < 8; ++j)
                    acc[i][j] = fmaf(av[i], bv[j], acc[i][j]);
        }
        __syncthreads();
    }

    const int b  = row0 >> 15;
    const int n0 = (row0 & (N_-1)) + tr*8;
    #pragma unroll
    for (int j = 0; j < 8; ++j) {
        int o = tc*8 + j;
        float bias = b2[o];
        float4 o0 = make_float4(acc[0][j]+bias, acc[1][j]+bias,
                                acc[2][j]+bias, acc[3][j]+bias);
        float4 o1 = make_float4(acc[4][j]+bias, acc[5][j]+bias,
                                acc[6][j]+bias, acc[7][j]+bias);
        float* dst = out + (((size_t)(b*OUT_ + o)) << 15) + n0;
        *(float4*)dst       = o0;
        *(float4*)(dst + 4) = o1;
    }
}

extern "C" void kernel_launch(void* const* d_in, const int* in_sizes, int n_in,
                              void* d_out, int out_size, void* d_ws, size_t ws_size,
                              hipStream_t stream) {
    const float* x        = (const float*)d_in[0];   // [B,N,3]
    const float* sx       = (const float*)d_in[1];   // [B,M,3]
    const float* features = (const float*)d_in[2];   // [B,M,C]
    const float* w1       = (const float*)d_in[3];   // [128,131]
    const float* b1       = (const float*)d_in[4];   // [128]
    const float* w2       = (const float*)d_in[5];   // [128,128]
    const float* b2       = (const float*)d_in[6];   // [128]
    float* out = (float*)d_out;                      // [B,128,N]

    char* ws = (char*)d_ws;
    // Layout:
    //   [0,1MB)     idx
    //   [2,6MB)     G        (4 MB)
    //   [6,38MB)    H        (32 MB; part_d/part_i dead after merge)
    //   [33,49MB)   part_d   (dead after merge)
    //   [49,65MB)   part_i   (dead after merge)
    int4*   idxb   = (int4*)ws;
    float*  G      = (float*)(ws + (2u  << 20));
    float*  Hbuf   = (float*)(ws + (6u  << 20));
    float4* part_d = (float4*)(ws + (33u << 20));
    int4*   part_i = (int4*) (ws + (33u << 20) + (16u<<20));

    nn_split_kernel<<<dim3((NQ/1024) * NSPLIT), dim3(256), 0, stream>>>(x, sx, part_d, part_i);
    merge_kernel   <<<dim3(NQ/256), dim3(256), 0, stream>>>(part_d, part_i, idxb);
    pre_gemm_kernel<<<dim3(B_*M_/128), dim3(256), 0, stream>>>(features, w1, G);
    hbuild_kernel  <<<dim3(NQ/8), dim3(256), 0, stream>>>(G, idxb, x, w1, b1, (float4*)Hbuf);
    gemm2_kernel   <<<dim3(NQ/128), dim3(256), 0, stream>>>(Hbuf, w2, b2, out);
}

// Round 12
// 244.400 us; speedup vs baseline: 1.3288x; 1.1245x over previous
//
#include <hip/hip_runtime.h>

#define B_   2
#define N_   32768
#define M_   4096
#define C_   128
#define OUT_ 128
#define IN_  131

#define NSPLIT 16
#define MCHUNK (M_ / NSPLIT)     // 256 points per split
#define NQ     (B_ * N_)         // 65536 total queries

// ---------------------------------------------------------------------------
// K1: split brute-force 3-NN, branchless top-3, explicit scalar state.
// (byte-identical to R11's passing kernel — control)
// ---------------------------------------------------------------------------
#define NN_DECL(X)                                                        \
    float x0##X, x1##X, x2##X, xx##X;                                     \
    float bd0##X = 1e30f, bd1##X = 1e30f, bd2##X = 1e30f;                 \
    int   bi0##X = 0,     bi1##X = 0,     bi2##X = 0;

#define NN_LOAD(X, QQ) {                                                  \
    const int qi = q0 + (QQ) * 256 + t;                                   \
    x0##X = x[(size_t)qi*3+0];                                            \
    x1##X = x[(size_t)qi*3+1];                                            \
    x2##X = x[(size_t)qi*3+2];                                            \
    xx##X = __fadd_rn(__fadd_rn(__fmul_rn(x0##X,x0##X),                   \
                                __fmul_rn(x1##X,x1##X)),                  \
                      __fmul_rn(x2##X,x2##X)); }

#define NN_STEP(X) {                                                      \
    float dot = __fadd_rn(__fadd_rn(__fmul_rn(x0##X,s.x),                 \
                                    __fmul_rn(x1##X,s.y)),                \
                          __fmul_rn(x2##X,s.z));                          \
    float d2 = __fadd_rn(__fmaf_rn(-2.0f, dot, xx##X), s.w);              \
    const float k0 = bd0##X, k1 = bd1##X, k2 = bd2##X;                    \
    const bool c0 = d2 < k0, c1 = d2 < k1, c2 = d2 < k2;                  \
    bi2##X = c1 ? bi1##X : (c2 ? m : bi2##X);                             \
    bi1##X = c0 ? bi0##X : (c1 ? m : bi1##X);                             \
    bi0##X = c0 ? m : bi0##X;                                             \
    bd0##X = fminf(k0, d2);                                               \
    bd1##X = __builtin_amdgcn_fmed3f(d2, k0, k1);                         \
    bd2##X = __builtin_amdgcn_fmed3f(d2, k1, k2); }

#define NN_STORE(X, QQ) {                                                 \
    const int qi = q0 + (QQ) * 256 + t;                                   \
    part_d[(size_t)split * NQ + qi] =                                     \
        make_float4(bd0##X, bd1##X, bd2##X, 0.f);                         \
    part_i[(size_t)split * NQ + qi] =                                     \
        make_int4(bi0##X, bi1##X, bi2##X, 0); }

__global__ __launch_bounds__(256, 4) void nn_split_kernel(const float* __restrict__ x,
                                                          const float* __restrict__ sx,
                                                          float4* __restrict__ part_d,
                                                          int4* __restrict__ part_i) {
    __shared__ float4 spts[MCHUNK];   // 4 KB
    const int split = blockIdx.x & (NSPLIT - 1);
    const int qb    = blockIdx.x >> 4;
    const int q0    = qb * 1024;
    const int b     = q0 >> 15;                     // N_=32768
    const int t     = threadIdx.x;

    // stage + pack this split's points (|s|^2 in reference rounding order)
    {
        const float* sp = sx + ((size_t)b * M_ + split * MCHUNK + t) * 3;
        float s0 = sp[0], s1 = sp[1], s2 = sp[2];
        float ss = __fadd_rn(__fadd_rn(__fmul_rn(s0,s0), __fmul_rn(s1,s1)),
                             __fmul_rn(s2,s2));
        spts[t] = make_float4(s0, s1, s2, ss);
    }
    __syncthreads();

    NN_DECL(A) NN_DECL(B) NN_DECL(C) NN_DECL(D)
    NN_LOAD(A, 0) NN_LOAD(B, 1) NN_LOAD(C, 2) NN_LOAD(D, 3)

    const int m_base = split * MCHUNK;
    #pragma unroll 2
    for (int j = 0; j < MCHUNK; ++j) {
        const float4 s = spts[j];
        const int m = m_base + j;
        NN_STEP(A) NN_STEP(B) NN_STEP(C) NN_STEP(D)
    }

    NN_STORE(A, 0) NN_STORE(B, 1) NN_STORE(C, 2) NN_STORE(D, 3)
}

// ---------------------------------------------------------------------------
// K2a: G = features @ W1f^T over all B*M sampled points (8192 rows, K=128).
// (unchanged)
// ---------------------------------------------------------------------------
__global__ __launch_bounds__(256) void pre_gemm_kernel(const float* __restrict__ features,
                                                       const float* __restrict__ w1,
                                                       float* __restrict__ G) {
    __shared__ float sI[16][132];
    __shared__ float sW[16][132];
    const int row0 = blockIdx.x * 128;
    const int tid  = threadIdx.x;
    const int tr   = tid & 15;
    const int tc   = tid >> 4;
    float acc[8][8] = {};

    for (int kc = 0; kc < 8; ++kc) {
        #pragma unroll
        for (int j = 0; j < 2; ++j) {
            int id  = j * 256 + tid;
            int row = id >> 2, kq = id & 3;
            float4 g = ((const float4*)features)[(size_t)(row0 + row) * 32 + kc * 4 + kq];
            sI[kq*4+0][row] = g.x; sI[kq*4+1][row] = g.y;
            sI[kq*4+2][row] = g.z; sI[kq*4+3][row] = g.w;
        }
        {
            int o = tid >> 1, kk0 = (tid & 1) * 8;
            #pragma unroll
            for (int kk = 0; kk < 8; ++kk)
                sW[kk0+kk][o] = w1[(size_t)o * IN_ + 3 + kc*16 + kk0 + kk];
        }
        __syncthreads();
        #pragma unroll
        for (int kk = 0; kk < 16; ++kk) {
            float4 a0 = *(const float4*)&sI[kk][tr*8];
            float4 a1 = *(const float4*)&sI[kk][tr*8+4];
            float4 c0 = *(const float4*)&sW[kk][tc*8];
            float4 c1 = *(const float4*)&sW[kk][tc*8+4];
            float av[8] = {a0.x,a0.y,a0.z,a0.w,a1.x,a1.y,a1.z,a1.w};
            float bv[8] = {c0.x,c0.y,c0.z,c0.w,c1.x,c1.y,c1.z,c1.w};
            #pragma unroll
            for (int i = 0; i < 8; ++i)
                #pragma unroll
                for (int j = 0; j < 8; ++j)
                    acc[i][j] = fmaf(av[i], bv[j], acc[i][j]);
        }
        __syncthreads();
    }

    #pragma unroll
    for (int i = 0; i < 8; ++i) {
        int r = row0 + tr*8 + i;
        float4 o0 = make_float4(acc[i][0], acc[i][1], acc[i][2], acc[i][3]);
        float4 o1 = make_float4(acc[i][4], acc[i][5], acc[i][6], acc[i][7]);
        ((float4*)G)[(size_t)r * 32 + tc*2 + 0] = o0;
        ((float4*)G)[(size_t)r * 32 + tc*2 + 1] = o1;
    }
}

// ---------------------------------------------------------------------------
// K3 (fused tail): merge + H-on-the-fly + gemm2 + transposed store.
// Per 128-query block:
//   Phase 0: threads 0-127 merge the 16 partial top-3s for one query each
//            (ascending-m + strict '<' = exact single-pass semantics) into
//            LDS sIdx; also stage x into sX. Threads 128-255 stage the
//            (w1-xyz, b1) table concurrently.
//   kc loop: instead of loading H from global, each chunk's sA[16][132] is
//            computed in place: gather G[idx] (L2-resident, 4MB) + H formula
//            (char-identical to R10/R11 hbuild). W2 staging, FMA core,
//            barriers and epilogue are byte-identical to the proven gemm2.
// Eliminates: merge+hbuild kernels, idx buffer, 64 MB H round-trip.
// LDS 22.9 KB -> ~5 blocks/CU (R9 lesson: stay small).
// ---------------------------------------------------------------------------
__global__ __launch_bounds__(256) void fused_tail_kernel(const float4* __restrict__ part_d,
                                                         const int4* __restrict__ part_i,
                                                         const float* __restrict__ G,
                                                         const float* __restrict__ x,
                                                         const float* __restrict__ w1,
                                                         const float* __restrict__ b1,
                                                         const float* __restrict__ w2,
                                                         const float* __restrict__ b2,
                                                         float* __restrict__ out) {
    __shared__ float  sA[16][132];    // H chunk [k][row]
    __shared__ float  sW[16][132];    // w2 chunk [k][out]
    __shared__ int4   sIdx[128];      // merged top-3 per query
    __shared__ float4 sX[128];        // query coords
    __shared__ float4 sWX[128];       // (wx0,wx1,wx2,b1) per channel
    const int row0 = blockIdx.x * 128;
    const int tid  = threadIdx.x;
    const int tr   = tid & 15;
    const int tc   = tid >> 4;
    const int b    = row0 >> 15;

    // ---- Phase 0: merge (threads 0-127) || stage w1-xyz table (128-255) ----
    if (tid < 128) {
        const int q = row0 + tid;
        float b0 = 1e30f, b1v = 1e30f, b2v = 1e30f;
        int   i0 = 0,     i1 = 0,      i2 = 0;
        #pragma unroll
        for (int s = 0; s < NSPLIT; ++s) {
            float4 d = part_d[(size_t)s * NQ + q];
            int4   i = part_i[(size_t)s * NQ + q];
            // ins3 inlined (ascending rank, strict '<')
            if (d.x < b2v) { if (d.x < b1v) { b2v=b1v; i2=i1;
                if (d.x < b0) { b1v=b0; i1=i0; b0=d.x; i0=i.x; }
                else          { b1v=d.x; i1=i.x; } } else { b2v=d.x; i2=i.x; } }
            if (d.y < b2v) { if (d.y < b1v) { b2v=b1v; i2=i1;
                if (d.y < b0) { b1v=b0; i1=i0; b0=d.y; i0=i.y; }
                else          { b1v=d.y; i1=i.y; } } else { b2v=d.y; i2=i.y; } }
            if (d.z < b2v) { if (d.z < b1v) { b2v=b1v; i2=i1;
                if (d.z < b0) { b1v=b0; i1=i0; b0=d.z; i0=i.z; }
                else          { b1v=d.z; i1=i.z; } } else { b2v=d.z; i2=i.z; } }
        }
        sIdx[tid] = make_int4(i0, i1, i2, 0);
        const float* xp = x + (size_t)q * 3;
        sX[tid] = make_float4(xp[0], xp[1], xp[2], 0.f);
    } else {
        const int c = tid - 128;
        sWX[c] = make_float4(w1[(size_t)c*IN_+0], w1[(size_t)c*IN_+1],
                             w1[(size_t)c*IN_+2], b1[c]);
    }
    __syncthreads();

    // ---- kc loop: build H chunk in LDS + stage w2 chunk, then FMA core ----
    const float4* gb = (const float4*)G + (size_t)b * M_ * 32;
    float acc[8][8] = {};
    for (int kc = 0; kc < 8; ++kc) {
        #pragma unroll
        for (int j = 0; j < 2; ++j) {
            int id  = j * 256 + tid;
            int row = id >> 2, kq = id & 3;
            const int c4 = kc * 4 + kq;          // channel-group [0,32)
            int4 v = sIdx[row];
            float4 a = gb[(size_t)v.x * 32 + c4];
            float4 e = gb[(size_t)v.y * 32 + c4];
            float4 f = gb[(size_t)v.z * 32 + c4];
            float4 xr = sX[row];
            float4 w0  = sWX[c4*4+0], w1v = sWX[c4*4+1];
            float4 w2v = sWX[c4*4+2], w3  = sWX[c4*4+3];
            float h;
            h = ((a.x + e.x) + f.x) * (1.0f/3.0f);
            h = fmaf(w0.x,xr.x, fmaf(w0.y,xr.y, fmaf(w0.z,xr.z, h))) + w0.w;
            sA[kq*4+0][row] = h > 0.0f ? h : 0.0f;
            h = ((a.y + e.y) + f.y) * (1.0f/3.0f);
            h = fmaf(w1v.x,xr.x, fmaf(w1v.y,xr.y, fmaf(w1v.z,xr.z, h))) + w1v.w;
            sA[kq*4+1][row] = h > 0.0f ? h : 0.0f;
            h = ((a.z + e.z) + f.z) * (1.0f/3.0f);
            h = fmaf(w2v.x,xr.x, fmaf(w2v.y,xr.y, fmaf(w2v.z,xr.z, h))) + w2v.w;
            sA[kq*4+2][row] = h > 0.0f ? h : 0.0f;
            h = ((a.w + e.w) + f.w) * (1.0f/3.0f);
            h = fmaf(w3.x,xr.x, fmaf(w3.y,xr.y, fmaf(w3.z,xr.z, h))) + w3.w;
            sA[kq*4+3][row] = h > 0.0f ? h : 0.0f;
            // w2 chunk (row = output channel here)
            float4 hh = ((const float4*)w2)[(size_t)row * 32 + kc * 4 + kq];
            sW[kq*4+0][row] = hh.x; sW[kq*4+1][row] = hh.y;
            sW[kq*4+2][row] = hh.z; sW[kq*4+3][row] = hh.w;
        }
        __syncthreads();
        #pragma unroll
        for (int kk = 0; kk < 16; ++kk) {
            float4 a0 = *(const float4*)&sA[kk][tr*8];
            float4 a1 = *(const float4*)&sA[kk][tr*8+4];
            float4 c0 = *(const float4*)&sW[kk][tc*8];
            float4 c1 = *(const float4*)&sW[kk][tc*8+4];
            float av[8] = {a0.x,a0.y,a0.z,a0.w,a1.x,a1.y,a1.z,a1.w};
            float bv[8] = {c0.x,c0.y,c0.z,c0.w,c1.x,c1.y,c1.z,c1.w};
            #pragma unroll
            for (int i = 0; i < 8; ++i)
                #pragma unroll
                for (int j = 0; j < 8; ++j)
                    acc[i][j] = fmaf(av[i], bv[j], acc[i][j]);
        }
        __syncthreads();
    }

    // ---- epilogue: bias + transposed store out[b][o][n] ----
    const int n0 = (row0 & (N_-1)) + tr*8;
    #pragma unroll
    for (int j = 0; j < 8; ++j) {
        int o = tc*8 + j;
        float bias = b2[o];
        float4 o0 = make_float4(acc[0][j]+bias, acc[1][j]+bias,
                                acc[2][j]+bias, acc[3][j]+bias);
        float4 o1 = make_float4(acc[4][j]+bias, acc[5][j]+bias,
                                acc[6][j]+bias, acc[7][j]+bias);
        float* dst = out + (((size_t)(b*OUT_ + o)) << 15) + n0;
        *(float4*)dst       = o0;
        *(float4*)(dst + 4) = o1;
    }
}

extern "C" void kernel_launch(void* const* d_in, const int* in_sizes, int n_in,
                              void* d_out, int out_size, void* d_ws, size_t ws_size,
                              hipStream_t stream) {
    const float* x        = (const float*)d_in[0];   // [B,N,3]
    const float* sx       = (const float*)d_in[1];   // [B,M,3]
    const float* features = (const float*)d_in[2];   // [B,M,C]
    const float* w1       = (const float*)d_in[3];   // [128,131]
    const float* b1       = (const float*)d_in[4];   // [128]
    const float* w2       = (const float*)d_in[5];   // [128,128]
    const float* b2       = (const float*)d_in[6];   // [128]
    float* out = (float*)d_out;                      // [B,128,N]

    char* ws = (char*)d_ws;
    // Layout:
    //   [2,6MB)     G        (4 MB)
    //   [33,49MB)   part_d
    //   [49,65MB)   part_i
    float*  G      = (float*)(ws + (2u  << 20));
    float4* part_d = (float4*)(ws + (33u << 20));
    int4*   part_i = (int4*) (ws + (33u << 20) + (16u<<20));

    nn_split_kernel <<<dim3((NQ/1024) * NSPLIT), dim3(256), 0, stream>>>(x, sx, part_d, part_i);
    pre_gemm_kernel <<<dim3(B_*M_/128), dim3(256), 0, stream>>>(features, w1, G);
    fused_tail_kernel<<<dim3(NQ/128), dim3(256), 0, stream>>>(part_d, part_i, G, x,
                                                              w1, b1, w2, b2, out);
}